// Round 3
// baseline (278.575 us; speedup 1.0000x reference)
//
#include <hip/hip_runtime.h>

// Problem constants (fixed by the reference setup_inputs()).
constexpr int B  = 2;
constexpr int A  = 512;
constexpr int P  = 8;
constexpr int CM = 6;     // cameras
constexpr int SC = 4;     // scales
constexpr int C  = 256;   // channels
constexpr int G  = 8;     // groups (D = 32 channels each)
constexpr int NCOMBO = P * CM * SC;      // 192
constexpr int NFEAT  = 89760;            // flattened feature rows per batch
constexpr int COMBOS_PER_WAVE = NCOMBO / 4;  // 48

__global__ __launch_bounds__(256)
void deform_agg_kernel(const float* __restrict__ feat,        // [B, NFEAT, C]
                       const int*   __restrict__ spatial,     // [CM, SC, 2] (H, W)
                       const int*   __restrict__ scale_start, // [CM, SC]
                       const float* __restrict__ samp_loc,    // [B, A, P, CM, 2]
                       const float* __restrict__ weights,     // [B, A, P, CM, S, G]
                       float*       __restrict__ out) {       // [B, A, C]
  __shared__ int    s_idx[NCOMBO][4];   // corner row index * (C/4)
  __shared__ float  s_cw[NCOMBO][4];    // corner bilinear weights (0 if invalid)
  __shared__ float  s_wg[NCOMBO * G];   // group weights, combo-major
  __shared__ float4 s_red[4][64];

  const int tid = threadIdx.x;
  const int ba  = blockIdx.x;       // b*A + a
  const int b   = ba >> 9;          // / 512

  // ---------------- stage 1: per-combo geometry ----------------
  if (tid < NCOMBO) {
    const int p   = tid / (CM * SC);
    const int cam = (tid / SC) % CM;
    const int s   = tid & (SC - 1);
    const float* lp = samp_loc + ((size_t)(ba * P + p) * CM + cam) * 2;
    const float lx = lp[0];
    const float ly = lp[1];
    const int H  = spatial[(cam * SC + s) * 2 + 0];
    const int W  = spatial[(cam * SC + s) * 2 + 1];
    const int st = scale_start[cam * SC + s];

    const float x = lx * (float)W - 0.5f;
    const float y = ly * (float)H - 0.5f;
    const float x0f = floorf(x), y0f = floorf(y);
    const int   ix0 = (int)x0f,  iy0 = (int)y0f;
    const float wx1 = x - x0f,   wy1 = y - y0f;
    const float wx[2] = {1.f - wx1, wx1};
    const float wy[2] = {1.f - wy1, wy1};
    const int   ix[2] = {ix0, ix0 + 1};
    const int   iy[2] = {iy0, iy0 + 1};
#pragma unroll
    for (int cyi = 0; cyi < 2; ++cyi) {
#pragma unroll
      for (int cxi = 0; cxi < 2; ++cxi) {
        const int k  = cyi * 2 + cxi;
        const int cx = ix[cxi], cy = iy[cyi];
        const bool valid = (cx >= 0) && (cx < W) && (cy >= 0) && (cy < H);
        const int ccx = min(max(cx, 0), W - 1);
        const int ccy = min(max(cy, 0), H - 1);
        s_idx[tid][k] = (st + ccy * W + ccx) * (C / 4);
        s_cw[tid][k]  = valid ? wx[cxi] * wy[cyi] : 0.f;
      }
    }
  }
  // weights for this (b,a): 1536 contiguous floats, layout == combo*G + g
  {
    const float* wbase = weights + (size_t)ba * NCOMBO * G;
    for (int i = tid; i < NCOMBO * G; i += 256) s_wg[i] = wbase[i];
  }
  __syncthreads();

  // ---------------- stage 2: gather + weighted accumulate ----------------
  const int wid  = tid >> 6;
  const int lane = tid & 63;
  const int g    = lane >> 3;   // channels [4*lane, 4*lane+4) -> group (4*lane)>>5
  const float4* fb = (const float4*)(feat + (size_t)b * NFEAT * C);

  float4 acc = {0.f, 0.f, 0.f, 0.f};
  const int c0 = wid * COMBOS_PER_WAVE;
#pragma unroll 4
  for (int cb = c0; cb < c0 + COMBOS_PER_WAVE; ++cb) {
    const float w   = s_wg[cb * G + g];
    const float cw0 = s_cw[cb][0] * w;
    const float cw1 = s_cw[cb][1] * w;
    const float cw2 = s_cw[cb][2] * w;
    const float cw3 = s_cw[cb][3] * w;
    const float4 f0 = fb[s_idx[cb][0] + lane];
    const float4 f1 = fb[s_idx[cb][1] + lane];
    const float4 f2 = fb[s_idx[cb][2] + lane];
    const float4 f3 = fb[s_idx[cb][3] + lane];
    acc.x = fmaf(f0.x, cw0, acc.x);
    acc.y = fmaf(f0.y, cw0, acc.y);
    acc.z = fmaf(f0.z, cw0, acc.z);
    acc.w = fmaf(f0.w, cw0, acc.w);
    acc.x = fmaf(f1.x, cw1, acc.x);
    acc.y = fmaf(f1.y, cw1, acc.y);
    acc.z = fmaf(f1.z, cw1, acc.z);
    acc.w = fmaf(f1.w, cw1, acc.w);
    acc.x = fmaf(f2.x, cw2, acc.x);
    acc.y = fmaf(f2.y, cw2, acc.y);
    acc.z = fmaf(f2.z, cw2, acc.z);
    acc.w = fmaf(f2.w, cw2, acc.w);
    acc.x = fmaf(f3.x, cw3, acc.x);
    acc.y = fmaf(f3.y, cw3, acc.y);
    acc.z = fmaf(f3.z, cw3, acc.z);
    acc.w = fmaf(f3.w, cw3, acc.w);
  }

  s_red[wid][lane] = acc;
  __syncthreads();

  if (wid == 0) {
    const float4 r0 = s_red[0][lane];
    const float4 r1 = s_red[1][lane];
    const float4 r2 = s_red[2][lane];
    const float4 r3 = s_red[3][lane];
    float4 t;
    t.x = (r0.x + r1.x) + (r2.x + r3.x);
    t.y = (r0.y + r1.y) + (r2.y + r3.y);
    t.z = (r0.z + r1.z) + (r2.z + r3.z);
    t.w = (r0.w + r1.w) + (r2.w + r3.w);
    ((float4*)out)[(size_t)ba * (C / 4) + lane] = t;
  }
}

extern "C" void kernel_launch(void* const* d_in, const int* in_sizes, int n_in,
                              void* d_out, int out_size, void* d_ws, size_t ws_size,
                              hipStream_t stream) {
  const float* feat        = (const float*)d_in[0];
  const int*   spatial     = (const int*)d_in[1];
  const int*   scale_start = (const int*)d_in[2];
  const float* samp_loc    = (const float*)d_in[3];
  const float* weights     = (const float*)d_in[4];
  float*       out         = (float*)d_out;

  deform_agg_kernel<<<B * A, 256, 0, stream>>>(feat, spatial, scale_start,
                                               samp_loc, weights, out);
}